// Round 1
// baseline (35182.187 us; speedup 1.0000x reference)
//
#include <hip/hip_runtime.h>
#include <math.h>

#define NL 10
#define C 128
#define CS 256
#define NV 256
#define NB 32
#define TT 1024
#define WPC 8
#define NTHR 256
#define CH_STRIDE 8192  // floats per chain-state block

// ---------------- atomic helpers (agent scope, relaxed: coherent across XCD L2s) ----
__device__ __forceinline__ float atomLoadF(const float* p) {
  return __hip_atomic_load(p, __ATOMIC_RELAXED, __HIP_MEMORY_SCOPE_AGENT);
}
__device__ __forceinline__ void atomStoreF(float* p, float v) {
  __hip_atomic_store(p, v, __ATOMIC_RELAXED, __HIP_MEMORY_SCOPE_AGENT);
}
__device__ __forceinline__ unsigned atomLoadU(const unsigned* p) {
  return __hip_atomic_load(p, __ATOMIC_RELAXED, __HIP_MEMORY_SCOPE_AGENT);
}
__device__ __forceinline__ void atomStoreU(unsigned* p, unsigned v) {
  __hip_atomic_store(p, v, __ATOMIC_RELAXED, __HIP_MEMORY_SCOPE_AGENT);
}

// per-chain barrier over WPC workgroups: monotonic counter, target tracked in regs.
// Every wave drains its own vmem (covers all threads' atomic data stores) before
// tid0 publishes arrival.
__device__ __forceinline__ void chainbar(unsigned* ctr, unsigned& target) {
  target += WPC;
  asm volatile("s_waitcnt vmcnt(0) lgkmcnt(0)" ::: "memory");
  __syncthreads();
  if (threadIdx.x == 0) {
    __hip_atomic_fetch_add(ctr, 1u, __ATOMIC_RELAXED, __HIP_MEMORY_SCOPE_AGENT);
    while (__hip_atomic_load(ctr, __ATOMIC_RELAXED, __HIP_MEMORY_SCOPE_AGENT) < target) {}
  }
  __syncthreads();
  asm volatile("" ::: "memory");
}

// ---------------- K1: embedding lookup ------------------------------------------
__global__ __launch_bounds__(256) void k_embed(const int* __restrict__ prompt,
                                               const float* __restrict__ E,
                                               float* __restrict__ X) {
  int idx = blockIdx.x * 256 + threadIdx.x;          // 262144 threads
  const float4* E4 = (const float4*)E;
  float4* X4 = (float4*)X;
#pragma unroll
  for (int p = 0; p < 4; ++p) {
    int i = idx + p * 262144;                        // over 1,048,576 float4 slots
    int row = i >> 5, c4 = i & 31;
    int tk = prompt[row];
    X4[i] = E4[tk * 32 + c4];
  }
}

// ---------------- K2: one dilated residual layer over full prompt ----------------
// block = 128 rows (one batch, 128 timesteps) x 256 cols (f|g), K=256 over {xd,x}.
// Fused: gate -> z, z@Wres + x + bres -> Xout, ring fill, zLast capture.
__global__ __launch_bounds__(256) void k_layer(
    const float* __restrict__ Xin, float* __restrict__ Xout,
    const float* __restrict__ Wf, const float* __restrict__ Wg,
    const float* __restrict__ bf, const float* __restrict__ bg,
    const float* __restrict__ Wres, const float* __restrict__ bres,
    float* __restrict__ rings, float* __restrict__ zlast, int l) {
  const int tid = threadIdx.x;
  const int m = blockIdx.x;
  const int b = m >> 3;
  const int t0 = (m & 7) << 7;
  const int d = 1 << l;

  __shared__ __align__(16) float sm[12416];
  float* Axd = sm;                 // [16][132] (ci-major, row padded)
  float* Ax  = sm + 16 * 132;     // [16][132]
  float* Wfs = sm + 32 * 132;     // [16][256]  (co*2+tap)
  float* Wgs = Wfs + 16 * 256;    // [16][256]

  const int rg = tid >> 4, cg = tid & 15;

  float af[8][8] = {};  // f accum, later reused as z
  float ag[8][8] = {};  // g accum, later reused as res accum

  for (int kc = 0; kc < 8; ++kc) {
    __syncthreads();
    // stage A tiles (x and x shifted by d), transposed to [ci][row]
#pragma unroll
    for (int p = 0; p < 2; ++p) {
      int li = tid + p * 256;             // 0..511
      int row = li >> 2, c4 = li & 3;
      int ci = kc * 16 + c4 * 4;
      int t = t0 + row;
      float4 vx = *(const float4*)(Xin + ((size_t)b * TT + t) * C + ci);
      float4 vd = make_float4(0.f, 0.f, 0.f, 0.f);
      int ts = t - d;
      if (ts >= 0) vd = *(const float4*)(Xin + ((size_t)b * TT + ts) * C + ci);
      Ax[(c4 * 4 + 0) * 132 + row] = vx.x;
      Ax[(c4 * 4 + 1) * 132 + row] = vx.y;
      Ax[(c4 * 4 + 2) * 132 + row] = vx.z;
      Ax[(c4 * 4 + 3) * 132 + row] = vx.w;
      Axd[(c4 * 4 + 0) * 132 + row] = vd.x;
      Axd[(c4 * 4 + 1) * 132 + row] = vd.y;
      Axd[(c4 * 4 + 2) * 132 + row] = vd.z;
      Axd[(c4 * 4 + 3) * 132 + row] = vd.w;
    }
    // stage W tiles: contiguous (co,tap) rows per ci
#pragma unroll
    for (int p = 0; p < 4; ++p) {
      int li = tid + p * 256;             // 0..1023
      int ci = li >> 6, cc = (li & 63) << 2;
      size_t off = ((size_t)(l * C + kc * 16 + ci) * C) * 2 + cc;
      *(float4*)&Wfs[ci * 256 + cc] = *(const float4*)(Wf + off);
      *(float4*)&Wgs[ci * 256 + cc] = *(const float4*)(Wg + off);
    }
    __syncthreads();
    for (int ci = 0; ci < 16; ++ci) {
      float4 d0 = *(float4*)&Axd[ci * 132 + rg * 8];
      float4 d1 = *(float4*)&Axd[ci * 132 + rg * 8 + 4];
      float4 x0 = *(float4*)&Ax[ci * 132 + rg * 8];
      float4 x1 = *(float4*)&Ax[ci * 132 + rg * 8 + 4];
      float axd[8] = {d0.x, d0.y, d0.z, d0.w, d1.x, d1.y, d1.z, d1.w};
      float ax[8]  = {x0.x, x0.y, x0.z, x0.w, x1.x, x1.y, x1.z, x1.w};
#pragma unroll
      for (int jj = 0; jj < 4; ++jj) {
        float4 wf = *(float4*)&Wfs[ci * 256 + cg * 16 + jj * 4];
        float4 wg = *(float4*)&Wgs[ci * 256 + cg * 16 + jj * 4];
#pragma unroll
        for (int i = 0; i < 8; ++i) {
          af[i][2 * jj]     += axd[i] * wf.x + ax[i] * wf.y;
          af[i][2 * jj + 1] += axd[i] * wf.z + ax[i] * wf.w;
          ag[i][2 * jj]     += axd[i] * wg.x + ax[i] * wg.y;
          ag[i][2 * jj + 1] += axd[i] * wg.z + ax[i] * wg.w;
        }
      }
    }
  }

  // gate in place: af <- z
  float bfv[8], bgv[8];
#pragma unroll
  for (int j = 0; j < 8; ++j) {
    bfv[j] = bf[l * C + cg * 8 + j];
    bgv[j] = bg[l * C + cg * 8 + j];
  }
#pragma unroll
  for (int i = 0; i < 8; ++i)
#pragma unroll
    for (int j = 0; j < 8; ++j) {
      float fv = tanhf(af[i][j] + bfv[j]);
      float gv = 1.f / (1.f + expf(-(ag[i][j] + bgv[j])));
      af[i][j] = fv * gv;
    }
  // capture z at t = T-1 for the tok0 head
  if (((m & 7) == 7) && rg == 15) {
#pragma unroll
    for (int j = 0; j < 8; ++j)
      zlast[((size_t)l * NB + b) * C + cg * 8 + j] = af[7][j];
  }
  // ag <- residual accum
#pragma unroll
  for (int i = 0; i < 8; ++i)
#pragma unroll
    for (int j = 0; j < 8; ++j) ag[i][j] = 0.f;

  // phase 2: z @ Wres in 4 chunks of 32 channels
  float* zs  = sm;              // [32][132]
  float* Wrs = sm + 32 * 132;   // [32][128]
  for (int c = 0; c < 4; ++c) {
    __syncthreads();
    if ((cg >> 2) == c) {
      int kl = (cg & 3) * 8;
#pragma unroll
      for (int i = 0; i < 8; ++i)
#pragma unroll
        for (int j = 0; j < 8; ++j) zs[(kl + j) * 132 + rg * 8 + i] = af[i][j];
    }
#pragma unroll
    for (int p = 0; p < 4; ++p) {
      int li = tid + p * 256;           // 0..1023
      int kr = li >> 5, cc = (li & 31) << 2;
      *(float4*)&Wrs[kr * 128 + cc] =
          *(const float4*)(Wres + ((size_t)(l * C + c * 32 + kr)) * C + cc);
    }
    __syncthreads();
    for (int k = 0; k < 32; ++k) {
      float4 a0 = *(float4*)&zs[k * 132 + rg * 8];
      float4 a1 = *(float4*)&zs[k * 132 + rg * 8 + 4];
      float4 w0 = *(float4*)&Wrs[k * 128 + cg * 8];
      float4 w1 = *(float4*)&Wrs[k * 128 + cg * 8 + 4];
      float a[8] = {a0.x, a0.y, a0.z, a0.w, a1.x, a1.y, a1.z, a1.w};
      float wv[8] = {w0.x, w0.y, w0.z, w0.w, w1.x, w1.y, w1.z, w1.w};
#pragma unroll
      for (int i = 0; i < 8; ++i)
#pragma unroll
        for (int j = 0; j < 8; ++j) ag[i][j] += a[i] * wv[j];
    }
  }

  // epilogue: Xout = Xin + bres + z@Wres ; ring fill (layer input = Xin)
  float brv[8];
#pragma unroll
  for (int j = 0; j < 8; ++j) brv[j] = bres[l * C + cg * 8 + j];
#pragma unroll
  for (int i = 0; i < 8; ++i) {
    int t = t0 + rg * 8 + i;
    const float4* xi = (const float4*)(Xin + ((size_t)b * TT + t) * C + cg * 8);
    float4 v0 = xi[0], v1 = xi[1];
    float o[8] = {v0.x, v0.y, v0.z, v0.w, v1.x, v1.y, v1.z, v1.w};
#pragma unroll
    for (int j = 0; j < 8; ++j) o[j] += brv[j] + ag[i][j];
    float4* xo = (float4*)(Xout + ((size_t)b * TT + t) * C + cg * 8);
    xo[0] = make_float4(o[0], o[1], o[2], o[3]);
    xo[1] = make_float4(o[4], o[5], o[6], o[7]);
    if (t >= TT - d) {
      int slot = t - (TT - d);
      float* rp = rings + (size_t)(d - 1) * NB * C + ((size_t)slot * NB + b) * C + cg * 8;
      *(float4*)&rp[0] = v0;
      *(float4*)&rp[4] = v1;
    }
  }
}

// ---------------- K3: skips@T-1 + head -> tok0 -----------------------------------
__global__ __launch_bounds__(256) void k_head0(
    const float* __restrict__ zlast, const float* __restrict__ Wskip,
    const float* __restrict__ bskip, const float* __restrict__ Wo1,
    const float* __restrict__ bo1, const float* __restrict__ Wo2,
    const float* __restrict__ bo2, float* __restrict__ chst,
    int* __restrict__ dout, int ostride) {
  int b = blockIdx.x, tid = threadIdx.x;
  __shared__ float zl[NL][C];
  __shared__ float sr[CS];
  __shared__ float h1[CS];
  __shared__ float lg[NV];
#pragma unroll
  for (int p = 0; p < 5; ++p) {
    int li = tid + p * 256;    // 0..1279
    zl[li >> 7][li & 127] = zlast[((size_t)(li >> 7) * NB + b) * C + (li & 127)];
  }
  __syncthreads();
  float s = 0.f;
  for (int l = 0; l < NL; ++l) {
    s += bskip[l * CS + tid];
    const float* wp = Wskip + (size_t)(l * C) * CS + tid;
    for (int k = 0; k < C; ++k) s += zl[l][k] * wp[(size_t)k * CS];
  }
  sr[tid] = fmaxf(s, 0.f);
  __syncthreads();
  float h = bo1[tid];
  {
    const float* wp = Wo1 + tid;
    for (int k = 0; k < CS; ++k) h += sr[k] * wp[(size_t)k * CS];
  }
  h1[tid] = fmaxf(h, 0.f);
  __syncthreads();
  float lv = bo2[tid];
  {
    const float* wp = Wo2 + tid;
    for (int k = 0; k < CS; ++k) lv += h1[k] * wp[(size_t)k * NV];
  }
  lg[tid] = lv;
  __syncthreads();
  if (tid == 0) {
    float bv = lg[0]; int bi = 0;
    for (int v = 1; v < NV; ++v)
      if (lg[v] > bv) { bv = lg[v]; bi = v; }
    ((unsigned*)(chst + (size_t)b * CH_STRIDE))[16] = (unsigned)bi;
    dout[(size_t)b * ostride + TT] = bi;
  }
}

// ---------------- K4: copy prompt into output ------------------------------------
__global__ __launch_bounds__(256) void k_copyprompt(const int* __restrict__ prompt,
                                                    int* __restrict__ dout,
                                                    int ostride) {
  int idx = blockIdx.x * 256 + threadIdx.x;  // 32768
  int b = idx >> 10, t = idx & 1023;
  dout[(size_t)b * ostride + t] = prompt[idx];
}

// ---------------- K5: persistent decode ------------------------------------------
// 32 chains x 8 WGs. WG w owns gate channels [16w,16w+16) of every layer and head
// columns [32w,32w+32). 12 chain-barriers per step.
__global__ __launch_bounds__(NTHR) void k_decode(
    const float* __restrict__ E, const float* __restrict__ Wf,
    const float* __restrict__ Wg, const float* __restrict__ bf,
    const float* __restrict__ bg, const float* __restrict__ Wres,
    const float* __restrict__ bres, const float* __restrict__ Wskip,
    const float* __restrict__ bskip, const float* __restrict__ Wo1,
    const float* __restrict__ bo1, const float* __restrict__ Wo2,
    const float* __restrict__ bo2, float* __restrict__ rings,
    float* __restrict__ chst, int* __restrict__ dout, int ostride) {
  const int tid = threadIdx.x;
  const int chain = blockIdx.x & 31;     // blockIdx%8 -> XCD: chain stays XCD-local
  const int w = blockIdx.x >> 5;
  const int nsteps = ostride - TT;

  float* st = chst + (size_t)chain * CH_STRIDE;
  unsigned* ctr = (unsigned*)st;
  float* xpart = st + 64;      // [2][8][128] (double-buffered by layer parity)
  float* skipp = st + 2176;    // [8][256]
  float* h1g   = st + 4224;    // [256]
  float* pmaxg = st + 4480;    // [8]
  unsigned* pidxg = (unsigned*)(st + 4488);  // [8]

  __shared__ float past[NL][C];
  __shared__ float xx[C];
  __shared__ float zbuf[16];
  __shared__ float fred[16][17];
  __shared__ float gred[16][17];
  __shared__ float skipr[CS];
  __shared__ float h1f[CS];
  __shared__ float hred[32][9];
  __shared__ float lgt[32];
  __shared__ float bsum[CS];
  __shared__ unsigned toksh;

  {
    float s = 0.f;
    for (int l = 0; l < NL; ++l) s += bskip[l * CS + tid];
    bsum[tid] = s;
  }
  __syncthreads();
  unsigned tok = ((const unsigned*)st)[16];   // tok0 from k_head0
  unsigned target = 0;

  const int col = tid & 15, kg = tid >> 4;    // gate-dot mapping
  const int hj = tid & 31, hkg = tid >> 5;    // head mapping

  for (int s = 0; s < nsteps - 1; ++s) {
    // prefetch current x = E[tok] and all 10 ring rows (slots known at step start)
    if (tid < C) xx[tid] = E[(size_t)tok * C + tid];
#pragma unroll
    for (int p = 0; p < 5; ++p) {
      int li = tid + p * NTHR;        // 0..1279
      int lp = li >> 7, cc = li & 127;
      int dd = 1 << lp;
      int slot = s & (dd - 1);
      past[lp][cc] = atomLoadF(
          &rings[(size_t)(dd - 1) * NB * C + (size_t)slot * NB * C + chain * C + cc]);
    }
    float skip_acc = 0.f;
    __syncthreads();

    for (int l = 0; l < NL; ++l) {
      // f/g dots for 16 channels co = 16w+col, K split over 16 kg groups
      const float* wfp = Wf + ((size_t)(l * C) * C + (w * 16 + col)) * 2;
      const float* wgp = Wg + ((size_t)(l * C) * C + (w * 16 + col)) * 2;
      float pf = 0.f, pg = 0.f;
#pragma unroll
      for (int i = 0; i < 8; ++i) {
        int ci = kg + 16 * i;
        float2 wf2 = *(const float2*)(wfp + (size_t)ci * C * 2);
        float2 wg2 = *(const float2*)(wgp + (size_t)ci * C * 2);
        float pv = past[l][ci], xv = xx[ci];
        pf += pv * wf2.x + xv * wf2.y;
        pg += pv * wg2.x + xv * wg2.y;
      }
      fred[col][kg] = pf;
      gred[col][kg] = pg;
      __syncthreads();
      if (tid < 16) {
        float sf = 0.f, sg = 0.f;
#pragma unroll
        for (int k = 0; k < 16; ++k) { sf += fred[tid][k]; sg += gred[tid][k]; }
        sf += bf[l * C + w * 16 + tid];
        sg += bg[l * C + w * 16 + tid];
        zbuf[tid] = tanhf(sf) * (1.f / (1.f + expf(-sg)));
      }
      __syncthreads();
      // skip contribution (thread owns skip column tid)
      {
        const float* wsp = Wskip + (size_t)(l * C + w * 16) * CS + tid;
        float a = 0.f;
#pragma unroll
        for (int j = 0; j < 16; ++j) a += zbuf[j] * wsp[(size_t)j * CS];
        skip_acc += a;
      }
      if (l < NL - 1) {
        float oldx = 0.f;
        if (tid < C) {
          const float* wrp = Wres + (size_t)(l * C + w * 16) * C + tid;
          float a = 0.f;
#pragma unroll
          for (int j = 0; j < 16; ++j) a += zbuf[j] * wrp[(size_t)j * C];
          atomStoreF(&xpart[((l & 1) * 8 + w) * C + tid], a);
          oldx = xx[tid];
        }
        chainbar(ctr, target);
        if (tid < C) {
          float nx = xx[tid] + bres[l * C + tid];
#pragma unroll
          for (int wi = 0; wi < 8; ++wi)
            nx += atomLoadF(&xpart[((l & 1) * 8 + wi) * C + tid]);
          if (w == 0) {
            int dd = 1 << l, slot = s & (dd - 1);
            atomStoreF(&rings[(size_t)(dd - 1) * NB * C + (size_t)slot * NB * C +
                              chain * C + tid],
                       oldx);
          }
          xx[tid] = nx;
        }
        __syncthreads();
      } else {
        // layer 9: no residual consumer; ring write only (x unchanged)
        if (w == 0 && tid < C) {
          int dd = 1 << l, slot = s & (dd - 1);
          atomStoreF(&rings[(size_t)(dd - 1) * NB * C + (size_t)slot * NB * C +
                            chain * C + tid],
                     xx[tid]);
        }
      }
    }

    // ---- head ----
    atomStoreF(&skipp[w * CS + tid], skip_acc);
    chainbar(ctr, target);  // #10
    {
      float sk = bsum[tid];
#pragma unroll
      for (int wi = 0; wi < 8; ++wi) sk += atomLoadF(&skipp[wi * CS + tid]);
      skipr[tid] = fmaxf(sk, 0.f);
    }
    __syncthreads();
    // h1 slice [32w, 32w+32)
    {
      const float* wp = Wo1 + w * 32 + hj;
      float a = 0.f;
      for (int k = hkg * 32; k < hkg * 32 + 32; ++k) a += skipr[k] * wp[(size_t)k * CS];
      hred[hj][hkg] = a;
      __syncthreads();
      if (tid < 32) {
        float v = 0.f;
#pragma unroll
        for (int k = 0; k < 8; ++k) v += hred[tid][k];
        v += bo1[w * 32 + tid];
        atomStoreF(&h1g[w * 32 + tid], fmaxf(v, 0.f));
      }
    }
    chainbar(ctr, target);  // #11
    h1f[tid] = atomLoadF(&h1g[tid]);
    __syncthreads();
    // logits slice + per-WG argmax
    {
      const float* wp = Wo2 + w * 32 + hj;
      float a = 0.f;
      for (int k = hkg * 32; k < hkg * 32 + 32; ++k) a += h1f[k] * wp[(size_t)k * NV];
      hred[hj][hkg] = a;
      __syncthreads();
      if (tid < 32) {
        float v = 0.f;
#pragma unroll
        for (int k = 0; k < 8; ++k) v += hred[tid][k];
        lgt[tid] = v + bo2[w * 32 + tid];
      }
      __syncthreads();
      if (tid == 0) {
        float bv = lgt[0]; int bi = 0;
        for (int j = 1; j < 32; ++j)
          if (lgt[j] > bv) { bv = lgt[j]; bi = j; }
        atomStoreF(&pmaxg[w], bv);
        atomStoreU(&pidxg[w], (unsigned)(w * 32 + bi));
      }
    }
    chainbar(ctr, target);  // #12
    // every WG reduces argmax redundantly (no extra barrier for tok broadcast)
    if (tid == 0) {
      float bv = atomLoadF(&pmaxg[0]);
      unsigned bi = atomLoadU(&pidxg[0]);
#pragma unroll
      for (int wi = 1; wi < 8; ++wi) {
        float v = atomLoadF(&pmaxg[wi]);
        if (v > bv) { bv = v; bi = atomLoadU(&pidxg[wi]); }
      }
      toksh = bi;
      if (w == 0) dout[(size_t)chain * ostride + TT + s + 1] = (int)bi;
    }
    __syncthreads();
    tok = toksh;
  }
}

// ---------------- host launcher ---------------------------------------------------
extern "C" void kernel_launch(void* const* d_in, const int* in_sizes, int n_in,
                              void* d_out, int out_size, void* d_ws, size_t ws_size,
                              hipStream_t stream) {
  const int* prompt = (const int*)d_in[0];
  const float* E    = (const float*)d_in[2];
  const float* Wf   = (const float*)d_in[3];
  const float* Wg   = (const float*)d_in[4];
  const float* bf   = (const float*)d_in[5];
  const float* bg   = (const float*)d_in[6];
  const float* Wres = (const float*)d_in[7];
  const float* bres = (const float*)d_in[8];
  const float* Wskip= (const float*)d_in[9];
  const float* bskip= (const float*)d_in[10];
  const float* Wo1  = (const float*)d_in[11];
  const float* bo1  = (const float*)d_in[12];
  const float* Wo2  = (const float*)d_in[13];
  const float* bo2  = (const float*)d_in[14];
  int* dout = (int*)d_out;
  int ostride = out_size / NB;  // TT + n_steps

  float* ws = (float*)d_ws;
  float* X0    = ws;                    // 4,194,304 floats
  float* X1    = ws + 4194304;          // 4,194,304
  float* rings = ws + 8388608;          // 4,190,208
  float* zlast = ws + 12578816;         // 40,960
  float* chst  = ws + 12619776;         // 32 * 8192

  hipMemsetAsync(chst, 0, (size_t)NB * CH_STRIDE * sizeof(float), stream);
  k_embed<<<1024, 256, 0, stream>>>(prompt, E, X0);
  float* xa = X0; float* xb = X1;
  for (int l = 0; l < NL; ++l) {
    k_layer<<<256, 256, 0, stream>>>(xa, xb, Wf, Wg, bf, bg, Wres, bres, rings, zlast, l);
    float* t = xa; xa = xb; xb = t;
  }
  k_head0<<<NB, 256, 0, stream>>>(zlast, Wskip, bskip, Wo1, bo1, Wo2, bo2, chst, dout, ostride);
  k_copyprompt<<<128, 256, 0, stream>>>(prompt, dout, ostride);
  k_decode<<<NB * WPC, NTHR, 0, stream>>>(E, Wf, Wg, bf, bg, Wres, bres, Wskip, bskip,
                                          Wo1, bo1, Wo2, bo2, rings, chst, dout, ostride);
}